// Round 2
// 73.294 us; speedup vs baseline: 1.0295x; 1.0295x over previous
//
#include <hip/hip_runtime.h>
#include <math.h>

#define NQ 12
#define TPB 256

// One 256-thread block (4 waves) per sample; 4096-amp state split 16-way:
// v[16] float2/thread = 32 VGPRs of state.
//
// Amp index j (12 bits), qubit q <-> j bit 11-q. Register layouts
// (t = thread 0..255 gives 8 bits, r = reg index 4 bits):
//   A: j = (r<<8)|t                  r = j[11:8] = qubits 0..3
//   B: j = (t[7:4]<<8)|(r<<4)|t[3:0] r = j[7:4]  = qubits 4..7
//   C: j = (t<<4)|r                  r = j[3:0]  = qubits 8..11
// B,C share wave bits j[11:10] -> B<->C roundtrips wave-local (no barrier).
//
// R11: ALL LDS addresses strength-reduced to base ^ compile-time-const.
// sg(j) = (j&~15)|((j^(j>>4)^(j>>8))&15) and the ring map P are GF(2)-
// linear, so with kC=(t^(t>>4))&15:
//   sg(J_A(r)) = VA ^ 257r,  VA = (t&0xF0)|kC
//   sg(J_B(r)) = VB ^ 17r,   VB = ((t>>4)<<8)|kC
//   sg(J_C(r)) = VC ^ r,     VC = (t<<4)|kC
//   sg(P(j))   = Ft ^ G(r<<8), Ft per-thread, G constant-folded
//
// R12/R13: kernel is issue-bound (R9/R10), so cut issue slots:
//  * M_GATE applies the raw SU(2) matrix [[a,-conj(b)],[b,conj(a)]] with
//    8 VOP3P pk ops/pair (op_sel swaps x<->y in-instruction, neg_lo/neg_hi
//    conjugates in-instruction) vs 12 mixed ops for the Euler form.
//  * Gate constants stored PRE-DUPLICATED ((ax,ax),(-ay,ay),...) in LDS;
//    each gate = broadcast ds_reads, zero rfl/v_mov construction.
//  * Measurement: partial WHT over reg bits (73 ops vs 112).
//  * Old B5 removed: post-ring store hits exactly the same addresses the
//    same thread read at the ring gather -> no cross-thread hazard.
//  * __launch_bounds__(256,4): VGPR cap 128 (grid/LDS limit occupancy to
//    4 blocks/CU anyway, so the headroom is free).
//  * R13 fix: FOR_PAIRS4 is variadic -- braces do NOT protect commas in
//    macro arguments (R12 compile failure).
//
// Circuit (algebra verified R2-R10): init(C) = L0 RX product state with
// ring0 FOLDED via inverse perm; fused M_q = RX(L1)*RZ(L0)*RY(L0) applied
// directly as SU(2); ring1 scatter; L1 RY (final RZ dropped -- phase-only);
// <Z_q> via partial reg-WHT + 6-stage lane-WHT butterfly.

__device__ __forceinline__ float2 pk_mul(float2 a, float2 b) {
    float2 d;
    asm("v_pk_mul_f32 %0, %1, %2" : "=v"(d) : "v"(a), "v"(b));
    return d;
}
__device__ __forceinline__ float2 pk_fma(float2 a, float2 b, float2 c) {
    float2 d;
    asm("v_pk_fma_f32 %0, %1, %2, %3" : "=v"(d) : "v"(a), "v"(b), "v"(c));
    return d;
}
// d.lo = a.hi*b.lo + c.lo ; d.hi = a.lo*b.hi + c.hi   (x<->y swap of a)
__device__ __forceinline__ float2 pk_fma_sw0(float2 a, float2 b, float2 c) {
    float2 d;
    asm("v_pk_fma_f32 %0, %1, %2, %3 op_sel:[1,0,0] op_sel_hi:[0,1,1]"
        : "=v"(d) : "v"(a), "v"(b), "v"(c));
    return d;
}
// d = a*(-b) + c
__device__ __forceinline__ float2 pk_fma_n1(float2 a, float2 b, float2 c) {
    float2 d;
    asm("v_pk_fma_f32 %0, %1, %2, %3 neg_lo:[0,1,0] neg_hi:[0,1,0]"
        : "=v"(d) : "v"(a), "v"(b), "v"(c));
    return d;
}
// d.lo = a.hi*(-b.lo) + c.lo ; d.hi = a.lo*(-b.hi) + c.hi
__device__ __forceinline__ float2 pk_fma_sw0n1(float2 a, float2 b, float2 c) {
    float2 d;
    asm("v_pk_fma_f32 %0, %1, %2, %3 op_sel:[1,0,0] op_sel_hi:[0,1,1] "
        "neg_lo:[0,1,0] neg_hi:[0,1,0]"
        : "=v"(d) : "v"(a), "v"(b), "v"(c));
    return d;
}

// variadic: commas inside the body are re-joined by __VA_ARGS__
#define FOR_PAIRS4(RB, ...) do {                                      \
    const int msk_ = 1 << (RB);                                       \
    _Pragma("unroll")                                                 \
    for (int h_ = 0; h_ < 8; ++h_) {                                  \
        const int i0 = ((h_ & ~(msk_ - 1)) << 1) | (h_ & (msk_ - 1)); \
        const int i1 = i0 | msk_;                                     \
        __VA_ARGS__;                                                  \
    } } while (0)

// strength-reduced swizzled addresses (VA/VB/VC/kC in scope)
#define ADDR_A(r) (VA ^ (257 * (r)))
#define ADDR_B(r) (VB ^ (17 * (r)))
#define ADDR_C(r) (VC ^ (r))

// wave-local roundtrip (same-wave LDS ordering, no barrier)
#define LOCAL_X(AS, AD) do {                                          \
    _Pragma("unroll")                                                 \
    for (int r_ = 0; r_ < 16; ++r_) S[AS(r_)] = v[r_];                \
    _Pragma("unroll")                                                 \
    for (int r_ = 0; r_ < 16; ++r_) v[r_] = S[AD(r_)];                \
  } while (0)

// SU(2) gate [[a, -conj(b)], [b, conj(a)]], a=(ax,ay), b=(bx,by).
// gm[q] = { (ax,ax), (-ay,ay), (bx,bx), (-by,by) }  (broadcast LDS reads)
//   n0 = a*v0 - conj(b)*v1 ; n1 = b*v0 + conj(a)*v1   (8 pk ops / pair)
#define M_GATE(q, RB) do {                                                  \
        const float2 ar = gm[q][0];                                         \
        const float2 ai = gm[q][1];                                         \
        const float2 br = gm[q][2];                                         \
        const float2 bi = gm[q][3];                                         \
        FOR_PAIRS4(RB,                                                      \
            const float2 v0 = v[i0];                                        \
            const float2 v1 = v[i1];                                        \
            float2 n0 = pk_mul(v0, ar);                                     \
            n0 = pk_fma_sw0(v0, ai, n0);                                    \
            n0 = pk_fma_n1(v1, br, n0);                                     \
            n0 = pk_fma_sw0(v1, bi, n0);                                    \
            float2 n1 = pk_mul(v0, br);                                     \
            n1 = pk_fma_sw0(v0, bi, n1);                                    \
            n1 = pk_fma(v1, ar, n1);                                        \
            n1 = pk_fma_sw0n1(v1, ai, n1);                                  \
            v[i0] = n0; v[i1] = n1;                                         \
        );                                                                  \
    } while (0)

// gy[q] = { (c,c), (s,s) } ; n0 = c*v0 - s*v1, n1 = s*v0 + c*v1
#define RY_GATE(q, RB) do {                                                 \
        const float2 c2 = gy[q][0];                                         \
        const float2 s2 = gy[q][1];                                         \
        FOR_PAIRS4(RB,                                                      \
            float2 n0 = pk_fma_n1(v[i1], s2, pk_mul(v[i0], c2));            \
            float2 n1 = pk_fma(v[i0], s2, pk_mul(v[i1], c2));               \
            v[i0] = n0; v[i1] = n1;                                         \
        );                                                                  \
    } while (0)

// phase: gate qubit QB+d on r-bit 3-d (holds for A, B, C alike)
#define M_PHASE(QB)  do { _Pragma("unroll")                                 \
    for (int d_ = 0; d_ < 4; ++d_) M_GATE((QB) + d_, 3 - d_); } while (0)
#define RY_PHASE(QB) do { _Pragma("unroll")                                 \
    for (int d_ = 0; d_ < 4; ++d_) RY_GATE((QB) + d_, 3 - d_); } while (0)

__global__ __launch_bounds__(TPB, 4) void vqc_kernel(
    const float* __restrict__ x,    // [B, 12]
    const float* __restrict__ th,   // [2, 12, 2]
    const float* __restrict__ lm,   // [2, 12]
    float* __restrict__ out)        // [B, 12]
{
    __shared__ float2 S[4096];
    __shared__ float2 gm[12][4];    // fused M gate, duplicated entries
    __shared__ float2 gy[12][2];    // L1 RY, duplicated (c,c),(s,s)
    __shared__ float2 coI[12];      // L0 RX half-angle (c,s)
    __shared__ float red[4 * 12];

    const int b = blockIdx.x;
    const int t = threadIdx.x;
    const int l = t & 63;
    const int w = t >> 6;

    // strength-reduced address bases
    const int kC = (t ^ (t >> 4)) & 15;
    const int VA = (t & 0xF0) | kC;
    const int VB = ((t >> 4) << 8) | kC;
    const int VC = (t << 4) | kC;
    // ring per-thread part: Ft = sg(P-image of t) (GF(2)-linear split)
    int Ft;
    {
        int yt = t ^ (t >> 1); yt ^= yt >> 2; yt ^= yt >> 4; yt ^= yt >> 8;
        int pt = (yt & 0x7FF) | ((__popc(t) & 1) << 11);
        Ft = (pt & ~15) | ((pt ^ (pt >> 4) ^ (pt >> 8)) & 15);
    }

    // ---- cooperative coefficient precompute ----
    if (t < 12) {
        float h = 0.5f * lm[t] * x[b * NQ + t];
        float c, s; __sincosf(h, &s, &c);
        coI[t] = make_float2(c, s);
    } else if (t < 24) {
        int q = t - 12;
        float h = 0.5f * th[24 + 2 * q];
        float c, s; __sincosf(h, &s, &c);
        gy[q][0] = make_float2(c, c);
        gy[q][1] = make_float2(s, s);
    } else if (t < 36) {
        int q = t - 24;
        float ha = 0.5f * lm[12 + q] * x[b * NQ + q];  // L1 RX half
        float hy = 0.5f * th[2 * q];                   // L0 RY half
        float hz = 0.5f * th[2 * q + 1];               // L0 RZ half
        float ca, sa, cy, sy, cz, sz;
        __sincosf(ha, &sa, &ca);
        __sincosf(hy, &sy, &cy);
        __sincosf(hz, &sz, &cz);
        // M = RX(a) RZ(z) RY(y) in SU(2): alpha = M00, beta = M10 (R9-verified)
        float ax = ca*cy*cz + sa*sy*sz;
        float ay = -(ca*cy*sz + sa*sy*cz);
        float bx = ca*sy*cz - sa*cy*sz;
        float by = ca*sy*sz - sa*cy*cz;
        gm[q][0] = make_float2(ax, ax);
        gm[q][1] = make_float2(-ay, ay);
        gm[q][2] = make_float2(bx, bx);
        gm[q][3] = make_float2(-by, by);
    }
    __syncthreads();                                   // B1

    float2 v[16];

    // ---- init in layout C: L0 RX product state, ring0 folded ----
    // (R10-verified) i = P^{-1}(j), j = (t<<4)|r:
    //  i0=r0^r1 (q11), i1=r1^r2 (q10), i2=r2^r3 (q9), i3=r3^t0 (q8),
    //  i4..i9 = gray(t) bits 0..5 (qubits 7..2),
    //  i10 = t6^r0^t7 (q1), i11 = r0^t7 (q0)
    {
        const int g = (t ^ (t >> 1)) & 0x3F;
        float Pt = 1.0f;
#pragma unroll
        for (int m = 0; m < 6; ++m) {
            float2 cs = coI[7 - m];
            Pt *= ((g >> m) & 1) ? cs.y : cs.x;
        }
        const int ct = __popc(g);
        const int t0 = t & 1, t7 = (t >> 7) & 1;
        const int e1 = ((t >> 6) ^ (t >> 7)) & 1;
        float2 q11 = coI[11], q10 = coI[10], q9 = coI[9],
               q8 = coI[8], q1 = coI[1], q0 = coI[0];
        const float u8  = t0 ? q8.y : q8.x;     // qubit 8, key t0^r3
        const float u8n = t0 ? q8.x : q8.y;
        const float u1  = e1 ? q1.y : q1.x;     // qubit 1, key e1^r0
        const float u1n = e1 ? q1.x : q1.y;
        const float u0  = t7 ? q0.y : q0.x;     // qubit 0, key t7^r0
        const float u0n = t7 ? q0.x : q0.y;
#pragma unroll
        for (int r = 0; r < 16; ++r) {
            const int r0 = r & 1, r1 = (r >> 1) & 1, r2 = (r >> 2) & 1,
                      r3 = (r >> 3) & 1;
            const int b11 = r0 ^ r1, b10 = r1 ^ r2, b9 = r2 ^ r3;
            float m = Pt * (b11 ? q11.y : q11.x) * (b10 ? q10.y : q10.x)
                         * (b9 ? q9.y : q9.x) * (r3 ? u8n : u8)
                         * (r0 ? u1n : u1) * (r0 ? u0n : u0);
            int k = (ct + b11 + b10 + b9 + (r3 ^ t0) + (r0 ^ e1) + (r0 ^ t7)) & 3;
            v[r].x = (k == 0) ? m : ((k == 2) ? -m : 0.0f);
            v[r].y = (k == 3) ? m : ((k == 1) ? -m : 0.0f);
        }
    }

    // ---- fused M-pass (L0 RY,RZ + L1 RX), C -> B -> A ----
    M_PHASE(8);                       // qubits 8..11 in C
    LOCAL_X(ADDR_C, ADDR_B);          // wave-local
    M_PHASE(4);                       // qubits 4..7  in B
#pragma unroll
    for (int r = 0; r < 16; ++r) S[ADDR_B(r)] = v[r];
    __syncthreads();                  // B2 (cross B -> A)
#pragma unroll
    for (int r = 0; r < 16; ++r) v[r] = S[ADDR_A(r)];
    M_PHASE(0);                       // qubits 0..3  in A

    // ---- layer-1 CNOT ring: A -> A (addr = Ft ^ const-folded G(r<<8)) ----
    __syncthreads();                  // B3 (all A-reads done before scatter)
#pragma unroll
    for (int r = 0; r < 16; ++r) {
        const int jr = r << 8;
        int yr = jr ^ (jr >> 1); yr ^= yr >> 2; yr ^= yr >> 4; yr ^= yr >> 8;
        const int pr = (yr & 0x7FF) | (((__popc(jr) ^ (jr >> 11)) & 1) << 11);
        const int Gr = (pr & ~15) | ((pr ^ (pr >> 4) ^ (pr >> 8)) & 15);
        S[Ft ^ Gr] = v[r];
    }
    __syncthreads();                  // B4
#pragma unroll
    for (int r = 0; r < 16; ++r) v[r] = S[ADDR_A(r)];

    // ---- layer-1 RY (final RZ dropped), A -> B -> C ----
    RY_PHASE(0);                      // in A
    // NOTE: no barrier here (old B5): the store below writes exactly the
    // addresses THIS thread read at the B4 gather -- per-wave in-order DS
    // + program order make it safe; no other thread touches these slots.
#pragma unroll
    for (int r = 0; r < 16; ++r) S[ADDR_A(r)] = v[r];
    __syncthreads();                  // B5 (cross A -> B)
#pragma unroll
    for (int r = 0; r < 16; ++r) v[r] = S[ADDR_B(r)];
    RY_PHASE(4);                      // in B
    LOCAL_X(ADDR_B, ADDR_C);          // wave-local
    RY_PHASE(8);                      // in C

    // ---- measurement in C ----
    // qubits 8..11 <-> r bits 3..0 ; qubits 2..7 <-> lane bits 5..0
    // (lane bit k = j[4+k] = qubit 7-k) ; qubits 0,1 <-> wave bits 1,0
    // Partial WHT over reg bits: 73 ops vs 112 for the naive signed sums.
    float p[16];
#pragma unroll
    for (int r = 0; r < 16; ++r)
        p[r] = fmaf(v[r].x, v[r].x, v[r].y * v[r].y);
    float sA[8], dA[8];
#pragma unroll
    for (int k = 0; k < 8; ++k) {
        sA[k] = p[2 * k] + p[2 * k + 1];
        dA[k] = p[2 * k] - p[2 * k + 1];
    }
    float z11 = ((dA[0] + dA[1]) + (dA[2] + dA[3]))
              + ((dA[4] + dA[5]) + (dA[6] + dA[7]));
    float sC[4], dC[4];
#pragma unroll
    for (int k = 0; k < 4; ++k) {
        sC[k] = sA[2 * k] + sA[2 * k + 1];
        dC[k] = sA[2 * k] - sA[2 * k + 1];
    }
    float z10 = (dC[0] + dC[1]) + (dC[2] + dC[3]);
    float e0 = sC[0] + sC[1], f0 = sC[0] - sC[1];
    float e1s = sC[2] + sC[3], f1 = sC[2] - sC[3];
    float vals[5];
    vals[0] = e0 + e1s;               // ptot
    vals[1] = e0 - e1s;               // z8  (r bit3)
    vals[2] = f0 + f1;                // z9  (r bit2)
    vals[3] = z10;                    // z10 (r bit1)
    vals[4] = z11;                    // z11 (r bit0)

    // 6-stage WHT butterfly: lane L ends with sum_l (-1)^{popc(L&l)} x_l
#pragma unroll
    for (int k = 0; k < 6; ++k) {
        const float sgn = ((l >> k) & 1) ? -1.f : 1.f;
#pragma unroll
        for (int m = 0; m < 5; ++m) {
            float tmp = __shfl_xor(vals[m], 1 << k, 64);
            vals[m] = fmaf(sgn, vals[m], tmp);
        }
    }
    if (l == 0) {                     // wave totals
        red[w * 12 + 0]  = vals[0];   // ptot (for qubits 0,1)
        red[w * 12 + 8]  = vals[1];
        red[w * 12 + 9]  = vals[2];
        red[w * 12 + 10] = vals[3];
        red[w * 12 + 11] = vals[4];
    } else if (__popc(l) == 1) {      // lane-bit sums: qubits 2..7
        int q = 8 - __ffs(l);         // l=1<<k -> q = 7-k
        red[w * 12 + q] = vals[0];
    }
    __syncthreads();                  // B6
    if (t < NQ) {
        float acc = 0.f;
#pragma unroll
        for (int ww = 0; ww < 4; ++ww) {
            if (t < 2) {
                float pv = red[ww * 12 + 0];
                acc += ((ww >> (1 - t)) & 1) ? -pv : pv;
            } else {
                acc += red[ww * 12 + t];
            }
        }
        out[b * NQ + t] = acc;
    }
}

extern "C" void kernel_launch(void* const* d_in, const int* in_sizes, int n_in,
                              void* d_out, int out_size, void* d_ws, size_t ws_size,
                              hipStream_t stream) {
    const int B = in_sizes[0] / NQ;  // 1024
    vqc_kernel<<<B, TPB, 0, stream>>>((const float*)d_in[0],
                                      (const float*)d_in[1],
                                      (const float*)d_in[2],
                                      (float*)d_out);
}